// Round 4
// baseline (146.772 us; speedup 1.0000x reference)
//
#include <hip/hip_runtime.h>
#include <hip/hip_bf16.h>
#include <hip/hip_cooperative_groups.h>
#include <math.h>

namespace cg = cooperative_groups;

#define BATCH 256
#define SEQL  4096
#define DIMC  256
#define NPAT  160
#define CNT   (BATCH * SEQL)     // per-stream element count (over B,L)
#define EPS   1e-3f

typedef unsigned int uint;
typedef unsigned short ushort_t;

// ---------------- shared helpers ----------------------------------------------
__device__ __forceinline__ int pad_mask(int type) {
    return (type == 0) ? 0 : (type == 1) ? 3 : (type == 2) ? 1 : (type == 3) ? 16 : 24;
}

__device__ __forceinline__ float tap6(int q, int k) {
    if (k == 5) return 1.0f;
    const int type = q >> 5, bits = q & 31;
    const int pm = pad_mask(type);
    if ((pm >> k) & 1) return 0.0f;
    return ((bits >> k) & 1) ? 1.0f : -1.0f;
}

__device__ __forceinline__ int tri_idx(int k, int l) {
    return k * 6 - (k * (k - 1)) / 2 + (l - k);
}

__device__ __forceinline__ float fast_elu(float x) {
    return x > 0.0f ? x : (__expf(x) - 1.0f);
}

__device__ __forceinline__ int pat_type(int t) {
    if (t >= 2 && t < SEQL - 2) return 0;
    if (t == 0) return 1;
    if (t == 1) return 2;
    if (t == SEQL - 2) return 3;
    return 4;
}

struct PtrPack { const float* p[18]; };  // per stream: Wc, bc, g, be, Wf, bf

// =============================================================================
// Cooperative single-dispatch pipeline
// =============================================================================
struct CoopArgs {
    const float* x;
    const int* perms;
    PtrPack pk;
    const float* Wm; const float* gm; const float* bem;
    const float* Wo; const float* bo; const float* go; const float* beo;
    uint*  part;     // [320][256]
    float* e_tab;    // [480]
    float* hrf;      // [480] reduced hist as float
    float* out_tab;  // [960]
    float* out;
};

struct ShmP1 { uint xw[130]; uint xwI[130]; uint h[2 * NPAT]; };
struct ShmP2 { float sn[NPAT]; float m6part[21][8]; float sM6[21];
               float sa[5][DIMC]; float sb[DIMC]; float swf[DIMC]; };
struct ShmP3 { float se[480]; float snn[480];
               float sA[DIMC], sB[DIMC], sWo0[DIMC], sWo1[DIMC];
               float spre0[480], spre1[480]; double wpart[8][4]; double dstat[6]; };
struct ShmP4 { float wtile[8][384]; float2 tb[480]; };
union ShmU { ShmP1 p1; ShmP2 p2; ShmP3 p3; ShmP4 p4; };

__global__ __launch_bounds__(512) void k_coop(CoopArgs a) {
    __shared__ ShmU u;
    const int b = blockIdx.x, tid = threadIdx.x;
    const int w = tid >> 6, lane = tid & 63;
    cg::grid_group grid = cg::this_grid();

    // ---------------- phase 1: pack bits, codes (registers), partial hist -----
    for (int i = tid; i < 2 * NPAT; i += 512) u.p1.h[i] = 0;
    if (tid < 2) { u.p1.xw[tid * 129] = 0; u.p1.xwI[tid * 129] = 0; }

    const float* xr = a.x + (size_t)b * SEQL;
    const int* pr = a.perms + (size_t)b * SEQL;

#pragma unroll
    for (int it = 0; it < 8; ++it) {
        const int i = it * 512 + tid;
        const unsigned long long m = __ballot(xr[i] > 0.5f);
        if (lane == 0) {
            const int wd = 1 + ((it * 512 + (tid & ~63)) >> 5);
            u.p1.xw[wd] = (uint)m;
            u.p1.xw[wd + 1] = (uint)(m >> 32);
        }
    }
    __syncthreads();
#pragma unroll
    for (int it = 0; it < 8; ++it) {
        const int i = it * 512 + tid;
        const int p = pr[i];
        const unsigned long long m = __ballot(((u.p1.xw[1 + (p >> 5)] >> (p & 31)) & 1u) != 0u);
        if (lane == 0) {
            const int wd = 1 + ((it * 512 + (tid & ~63)) >> 5);
            u.p1.xwI[wd] = (uint)m;
            u.p1.xwI[wd + 1] = (uint)(m >> 32);
        }
    }
    __syncthreads();

    // wave-stripe mapping: wave w covers [w*512, w*512+512), lane-consecutive per r
    uint cr[4];
#pragma unroll
    for (int r = 0; r < 8; ++r) {
        const int p = w * 512 + r * 64 + lane;
        const int bitpos = p + 30;
        const int wd = bitpos >> 5, sh = bitpos & 31;
        const unsigned long long Wd = (unsigned long long)u.p1.xw[wd] |
                                      ((unsigned long long)u.p1.xw[wd + 1] << 32);
        const unsigned long long Wi = (unsigned long long)u.p1.xwI[wd] |
                                      ((unsigned long long)u.p1.xwI[wd + 1] << 32);
        const int type = pat_type(p);
        const int qd = type * 32 + (int)((Wd >> sh) & 31ull);
        const int qp = type * 32 + (int)((Wi >> sh) & 31ull);
        atomicAdd(&u.p1.h[qd], 1u);
        atomicAdd(&u.p1.h[NPAT + qp], 1u);
        const uint code = (uint)(qd | (qp << 8));
        if (r & 1) cr[r >> 1] |= code << 16; else cr[r >> 1] = code;
    }
    __syncthreads();
    if (tid < 2 * NPAT) a.part[(size_t)tid * 256 + b] = u.p1.h[tid];

    grid.sync();

    // ---------------- phase 2: blocks 0..59 — hist reduce + BN + e-table ------
    if (blockIdx.x < 60) {
        const int j = blockIdx.x / 20;
        const int qbase = (blockIdx.x % 20) * 8;
        const float* Wc = a.pk.p[6 * j + 0];
        const float* bc = a.pk.p[6 * j + 1];
        const float* g  = a.pk.p[6 * j + 2];
        const float* be = a.pk.p[6 * j + 3];
        const float* Wf = a.pk.p[6 * j + 4];
        const float  bf = a.pk.p[6 * j + 5][0];
        const int base = (j == 2) ? NPAT : 0;

        for (int bl = w * 20; bl < w * 20 + 20; ++bl) {
            const uint4 v = *(const uint4*)&a.part[(size_t)(base + bl) * 256 + lane * 4];
            uint s = v.x + v.y + v.z + v.w;
#pragma unroll
            for (int off = 32; off; off >>= 1) s += __shfl_xor(s, off);
            if (lane == 0) {
                u.p2.sn[bl] = (float)s;
                if ((blockIdx.x % 20) == 0) a.hrf[j * NPAT + bl] = (float)s;
            }
        }
        __syncthreads();

        if (tid < 168) {
            const int e = tid >> 3, prt = tid & 7;
            int k = 0, rem = e;
            while (rem > 5 - k) { rem -= 6 - k; ++k; }
            const int l = k + rem;
            float S = 0.0f;
            for (int q = prt * 20; q < prt * 20 + 20; ++q)
                S += u.p2.sn[q] * tap6(q, k) * tap6(q, l);
            u.p2.m6part[e][prt] = S;
        }
        __syncthreads();
        if (tid < 21) {
            float S = 0.0f;
#pragma unroll
            for (int p = 0; p < 8; ++p) S += u.p2.m6part[tid][p];
            u.p2.sM6[tid] = S;
        }
        __syncthreads();

        if (tid < DIMC) {
            const int cch = tid;
            float w6[6];
#pragma unroll
            for (int k = 0; k < 5; ++k) w6[k] = Wc[k * DIMC + cch];
            w6[5] = bc[cch];
            double Ey = 0.0, Ey2 = 0.0;
            int e = 0;
            for (int k = 0; k < 6; ++k) {
                Ey += (double)w6[k] * (double)u.p2.sM6[tri_idx(k, 5)];
                for (int l = k; l < 6; ++l, ++e) {
                    const double p = (double)w6[k] * (double)w6[l] * (double)u.p2.sM6[e];
                    Ey2 += (l == k) ? p : 2.0 * p;
                }
            }
            const double mean = Ey / (double)CNT;
            const double var = Ey2 / (double)CNT - mean * mean;
            const float scale = g[cch] * rsqrtf((float)var + EPS);
#pragma unroll
            for (int k = 0; k < 5; ++k) u.p2.sa[k][cch] = scale * w6[k];
            u.p2.sb[cch] = scale * (w6[5] - (float)mean) + be[cch];
            u.p2.swf[cch] = Wf[cch];
        }
        __syncthreads();

        const int q = qbase + w;
        float tk[5];
#pragma unroll
        for (int k = 0; k < 5; ++k) tk[k] = tap6(q, k);
        float acc = 0.0f;
#pragma unroll
        for (int i = 0; i < 4; ++i) {
            const int cch = lane + 64 * i;
            float bn = u.p2.sb[cch];
#pragma unroll
            for (int k = 0; k < 5; ++k) bn += tk[k] * u.p2.sa[k][cch];
            acc += fast_elu(bn) * u.p2.swf[cch];
        }
#pragma unroll
        for (int off = 32; off; off >>= 1) acc += __shfl_xor(acc, off);
        if (lane == 0) a.e_tab[j * NPAT + q] = acc + bf;
    }

    grid.sync();

    // ---------------- phase 3: block 0 — middle+output units -> out_tab -------
    if (blockIdx.x == 0) {
        if (tid < 480) {
            u.p3.se[tid] = a.e_tab[tid];
            u.p3.snn[tid] = a.hrf[tid];
        }
        __syncthreads();

        double d1 = 0.0, d2 = 0.0;
        if (tid < 480) {
            const double n = (double)u.p3.snn[tid], e = (double)u.p3.se[tid];
            d1 = n * e; d2 = n * e * e;
        }
#pragma unroll
        for (int off = 32; off; off >>= 1) {
            d1 += __shfl_xor(d1, off);
            d2 += __shfl_xor(d2, off);
        }
        if (lane == 0) { u.p3.wpart[w][0] = d1; u.p3.wpart[w][1] = d2; }
        __syncthreads();
        if (w == 0) {
            double aa = (lane < 8) ? u.p3.wpart[lane][0] : 0.0;
            double bb = (lane < 8) ? u.p3.wpart[lane][1] : 0.0;
#pragma unroll
            for (int off = 4; off; off >>= 1) {
                aa += __shfl_xor(aa, off);
                bb += __shfl_xor(bb, off);
            }
            if (lane == 0) { u.p3.dstat[0] = aa; u.p3.dstat[1] = bb; }
        }
        __syncthreads();
        const double mean_yt = u.p3.dstat[0] / (3.0 * (double)CNT);
        const double var_yt  = u.p3.dstat[1] / (3.0 * (double)CNT) - mean_yt * mean_yt;

        if (tid < DIMC) {
            const float wm = a.Wm[tid];
            u.p3.sA[tid] = a.gm[tid] * wm * rsqrtf(wm * wm * (float)var_yt + EPS);
            u.p3.sB[tid] = a.bem[tid];
            u.p3.sWo0[tid] = a.Wo[tid * 2 + 0];
            u.p3.sWo1[tid] = a.Wo[tid * 2 + 1];
        }
        __syncthreads();

        const float bo0 = a.bo[0], bo1 = a.bo[1];
        for (int idx = w; idx < 480; idx += 8) {
            const float du = u.p3.se[idx] - (float)mean_yt;
            float a0 = 0.0f, a1 = 0.0f;
#pragma unroll
            for (int i = 0; i < 4; ++i) {
                const int cch = lane + 64 * i;
                const float mo = fast_elu(u.p3.sA[cch] * du + u.p3.sB[cch]);
                a0 += mo * u.p3.sWo0[cch];
                a1 += mo * u.p3.sWo1[cch];
            }
#pragma unroll
            for (int off = 32; off; off >>= 1) {
                a0 += __shfl_xor(a0, off);
                a1 += __shfl_xor(a1, off);
            }
            if (lane == 0) { u.p3.spre0[idx] = a0 + bo0; u.p3.spre1[idx] = a1 + bo1; }
        }
        __syncthreads();

        double v4[4] = {0.0, 0.0, 0.0, 0.0};
        if (tid < 480) {
            const double n = (double)u.p3.snn[tid];
            const double p0 = (double)u.p3.spre0[tid], p1 = (double)u.p3.spre1[tid];
            v4[0] = n * p0; v4[1] = n * p0 * p0; v4[2] = n * p1; v4[3] = n * p1 * p1;
        }
#pragma unroll
        for (int off = 32; off; off >>= 1)
#pragma unroll
            for (int s = 0; s < 4; ++s) v4[s] += __shfl_xor(v4[s], off);
        if (lane == 0)
#pragma unroll
            for (int s = 0; s < 4; ++s) u.p3.wpart[w][s] = v4[s];
        __syncthreads();
        if (w == 0) {
            double aa[4];
#pragma unroll
            for (int s = 0; s < 4; ++s) aa[s] = (lane < 8) ? u.p3.wpart[lane][s] : 0.0;
#pragma unroll
            for (int off = 4; off; off >>= 1)
#pragma unroll
                for (int s = 0; s < 4; ++s) aa[s] += __shfl_xor(aa[s], off);
            if (lane == 0)
#pragma unroll
                for (int s = 0; s < 4; ++s) u.p3.dstat[2 + s] = aa[s];
        }
        __syncthreads();

        if (tid < 480) {
            const double m0 = u.p3.dstat[2] / (3.0 * (double)CNT);
            const double v0 = u.p3.dstat[3] / (3.0 * (double)CNT) - m0 * m0;
            const double m1 = u.p3.dstat[4] / (3.0 * (double)CNT);
            const double v1 = u.p3.dstat[5] / (3.0 * (double)CNT) - m1 * m1;
            const float sc0 = a.go[0] * rsqrtf((float)v0 + EPS);
            const float sc1 = a.go[1] * rsqrtf((float)v1 + EPS);
            a.out_tab[tid * 2 + 0] = sc0 * (u.p3.spre0[tid] - (float)m0) + a.beo[0];
            a.out_tab[tid * 2 + 1] = sc1 * (u.p3.spre1[tid] - (float)m1) + a.beo[1];
        }
    }

    grid.sync();

    // ---------------- phase 4: decode codes, LDS tile, coalesced writes -------
    if (tid < 480) u.p4.tb[tid] = ((const float2*)a.out_tab)[tid];
    __syncthreads();

    float2* wt = (float2*)u.p4.wtile[w];   // 192 float2 per wave
#pragma unroll
    for (int r = 0; r < 8; ++r) {
        const uint code = (cr[r >> 1] >> ((r & 1) * 16)) & 0xffffu;
        const int qd = (int)(code & 0xffu), qp = (int)(code >> 8);
        wt[lane * 3 + 0] = u.p4.tb[qd];
        wt[lane * 3 + 1] = u.p4.tb[NPAT + qd];
        wt[lane * 3 + 2] = u.p4.tb[2 * NPAT + qp];
        float2* gd = (float2*)(a.out + ((size_t)b * SEQL + w * 512 + r * 64) * 6);
        gd[lane]       = wt[lane];
        gd[lane + 64]  = wt[lane + 64];
        gd[lane + 128] = wt[lane + 128];
    }
}

// =============================================================================
// Fallback path (round-3, proven): prep -> etab2 -> outtab2 -> write2
// =============================================================================
__global__ __launch_bounds__(512) void k_prep(const float* __restrict__ x,
                                              const int* __restrict__ perms,
                                              uint* __restrict__ part,
                                              ushort_t* __restrict__ codes) {
    __shared__ uint xw[130];
    __shared__ uint xwI[130];
    __shared__ uint h[2 * NPAT];
    const int b = blockIdx.x, tid = threadIdx.x;
    const int lane = tid & 63;

    for (int i = tid; i < 2 * NPAT; i += 512) h[i] = 0;
    if (tid < 2) { xw[tid * 129] = 0; xwI[tid * 129] = 0; }

    const float* xr = x + (size_t)b * SEQL;
    const int* pr = perms + (size_t)b * SEQL;

#pragma unroll
    for (int it = 0; it < 8; ++it) {
        const int i = it * 512 + tid;
        const unsigned long long m = __ballot(xr[i] > 0.5f);
        if (lane == 0) {
            const int w = 1 + ((it * 512 + (tid & ~63)) >> 5);
            xw[w] = (uint)m;
            xw[w + 1] = (uint)(m >> 32);
        }
    }
    __syncthreads();
#pragma unroll
    for (int it = 0; it < 8; ++it) {
        const int i = it * 512 + tid;
        const int p = pr[i];
        const unsigned long long m = __ballot(((xw[1 + (p >> 5)] >> (p & 31)) & 1u) != 0u);
        if (lane == 0) {
            const int w = 1 + ((it * 512 + (tid & ~63)) >> 5);
            xwI[w] = (uint)m;
            xwI[w + 1] = (uint)(m >> 32);
        }
    }
    __syncthreads();

    const int t0 = tid * 8;
    const int w = (t0 + 30) >> 5;
    const int sh0 = (t0 + 30) & 31;
    const unsigned long long Wd = (unsigned long long)xw[w] | ((unsigned long long)xw[w + 1] << 32);
    const unsigned long long Wi = (unsigned long long)xwI[w] | ((unsigned long long)xwI[w + 1] << 32);
    int c[8];
#pragma unroll
    for (int r = 0; r < 8; ++r) {
        const int t = t0 + r;
        const int type = pat_type(t);
        const int qd = type * 32 + (int)((Wd >> (sh0 + r)) & 31ull);
        const int qp = type * 32 + (int)((Wi >> (sh0 + r)) & 31ull);
        atomicAdd(&h[qd], 1u);
        atomicAdd(&h[NPAT + qp], 1u);
        c[r] = qd | (qp << 8);
    }
    uint4 cv;
    cv.x = (uint)(c[0] | (c[1] << 16));
    cv.y = (uint)(c[2] | (c[3] << 16));
    cv.z = (uint)(c[4] | (c[5] << 16));
    cv.w = (uint)(c[6] | (c[7] << 16));
    *(uint4*)(codes + (size_t)b * SEQL + t0) = cv;
    __syncthreads();

    if (tid < 2 * NPAT) part[(size_t)tid * 256 + b] = h[tid];
}

__global__ __launch_bounds__(256) void k_etab2(PtrPack pk,
                                               const uint* __restrict__ part,
                                               float* __restrict__ e_tab,
                                               uint* __restrict__ hr) {
    const int tid = threadIdx.x;
    const int j = blockIdx.x / 40;
    const int qbase = (blockIdx.x % 40) * 4;
    const int wv = tid >> 6, lane = tid & 63;
    const float* Wc = pk.p[6 * j + 0];
    const float* bc = pk.p[6 * j + 1];
    const float* g  = pk.p[6 * j + 2];
    const float* be = pk.p[6 * j + 3];
    const float* Wf = pk.p[6 * j + 4];
    const float  bf = pk.p[6 * j + 5][0];
    const int binBase = (j == 2) ? NPAT : 0;

    __shared__ float sn[NPAT];
    __shared__ float m6part[21][8];
    __shared__ float sM6[21];
    __shared__ float sa[5][DIMC];
    __shared__ float sb[DIMC];
    __shared__ float swf[DIMC];

    for (int p = 0; p < 40; ++p) {
        const int bl = p * 4 + wv;
        const uint4 v = *(const uint4*)&part[(size_t)(binBase + bl) * 256 + lane * 4];
        uint s = v.x + v.y + v.z + v.w;
#pragma unroll
        for (int off = 32; off; off >>= 1) s += __shfl_xor(s, off);
        if (lane == 0) {
            sn[bl] = (float)s;
            hr[binBase + bl] = s;
        }
    }
    __syncthreads();

    if (tid < 168) {
        const int e = tid >> 3, prt = tid & 7;
        int k = 0, rem = e;
        while (rem > 5 - k) { rem -= 6 - k; ++k; }
        const int l = k + rem;
        float S = 0.0f;
        for (int q = prt * 20; q < prt * 20 + 20; ++q)
            S += sn[q] * tap6(q, k) * tap6(q, l);
        m6part[e][prt] = S;
    }
    __syncthreads();
    if (tid < 21) {
        float S = 0.0f;
#pragma unroll
        for (int p = 0; p < 8; ++p) S += m6part[tid][p];
        sM6[tid] = S;
    }
    __syncthreads();

    {
        const int cch = tid;
        float w6[6];
#pragma unroll
        for (int k = 0; k < 5; ++k) w6[k] = Wc[k * DIMC + cch];
        w6[5] = bc[cch];
        double Ey = 0.0, Ey2 = 0.0;
        int e = 0;
        for (int k = 0; k < 6; ++k) {
            Ey += (double)w6[k] * (double)sM6[tri_idx(k, 5)];
            for (int l = k; l < 6; ++l, ++e) {
                const double p = (double)w6[k] * (double)w6[l] * (double)sM6[e];
                Ey2 += (l == k) ? p : 2.0 * p;
            }
        }
        const double mean = Ey / (double)CNT;
        const double var = Ey2 / (double)CNT - mean * mean;
        const float scale = g[cch] * rsqrtf((float)var + EPS);
#pragma unroll
        for (int k = 0; k < 5; ++k) sa[k][cch] = scale * w6[k];
        sb[cch] = scale * (w6[5] - (float)mean) + be[cch];
        swf[cch] = Wf[cch];
    }
    __syncthreads();

    const int q = qbase + wv;
    float tk[5];
#pragma unroll
    for (int k = 0; k < 5; ++k) tk[k] = tap6(q, k);
    float acc = 0.0f;
#pragma unroll
    for (int i = 0; i < 4; ++i) {
        const int cch = lane + 64 * i;
        float bn = sb[cch];
#pragma unroll
        for (int k = 0; k < 5; ++k) bn += tk[k] * sa[k][cch];
        acc += fast_elu(bn) * swf[cch];
    }
#pragma unroll
    for (int off = 32; off; off >>= 1) acc += __shfl_xor(acc, off);
    if (lane == 0) e_tab[j * NPAT + q] = acc + bf;
}

__global__ __launch_bounds__(1024) void k_outtab2(const uint* __restrict__ hr,
                                                  const float* __restrict__ e_tab,
                                                  const float* __restrict__ Wm,
                                                  const float* __restrict__ gm,
                                                  const float* __restrict__ bem,
                                                  const float* __restrict__ Wo,
                                                  const float* __restrict__ bo,
                                                  const float* __restrict__ go,
                                                  const float* __restrict__ beo,
                                                  float* __restrict__ out_tab) {
    const int tid = threadIdx.x;
    const int lane = tid & 63, wv = tid >> 6;

    __shared__ float se[3 * NPAT];
    __shared__ float snn[3 * NPAT];
    __shared__ float sA[DIMC], sB[DIMC], sWo0[DIMC], sWo1[DIMC];
    __shared__ float spre0[3 * NPAT], spre1[3 * NPAT];
    __shared__ double wpart[16][4];
    __shared__ double dstat[6];

    if (tid < 3 * NPAT) {
        se[tid] = e_tab[tid];
        snn[tid] = (float)hr[(tid >= 2 * NPAT) ? (tid - NPAT) : (tid % NPAT)];
    }
    __syncthreads();

    {
        double d1 = 0.0, d2 = 0.0;
        if (tid < 3 * NPAT) {
            const double n = (double)snn[tid], e = (double)se[tid];
            d1 = n * e; d2 = n * e * e;
        }
#pragma unroll
        for (int off = 32; off; off >>= 1) {
            d1 += __shfl_xor(d1, off);
            d2 += __shfl_xor(d2, off);
        }
        if (lane == 0) { wpart[wv][0] = d1; wpart[wv][1] = d2; }
        __syncthreads();
        if (wv == 0) {
            double aq = (lane < 16) ? wpart[lane][0] : 0.0;
            double bq = (lane < 16) ? wpart[lane][1] : 0.0;
#pragma unroll
            for (int off = 8; off; off >>= 1) {
                aq += __shfl_xor(aq, off);
                bq += __shfl_xor(bq, off);
            }
            if (lane == 0) { dstat[0] = aq; dstat[1] = bq; }
        }
        __syncthreads();
    }
    const double mean_yt = dstat[0] / (3.0 * (double)CNT);
    const double var_yt  = dstat[1] / (3.0 * (double)CNT) - mean_yt * mean_yt;

    if (tid < DIMC) {
        const float wm = Wm[tid];
        sA[tid] = gm[tid] * wm * rsqrtf(wm * wm * (float)var_yt + EPS);
        sB[tid] = bem[tid];
        sWo0[tid] = Wo[tid * 2 + 0];
        sWo1[tid] = Wo[tid * 2 + 1];
    }
    __syncthreads();

    const float bo0 = bo[0], bo1 = bo[1];
    for (int idx = wv; idx < 3 * NPAT; idx += 16) {
        const float du = se[idx] - (float)mean_yt;
        float a0 = 0.0f, a1 = 0.0f;
#pragma unroll
        for (int i = 0; i < 4; ++i) {
            const int cch = lane + 64 * i;
            const float mo = fast_elu(sA[cch] * du + sB[cch]);
            a0 += mo * sWo0[cch];
            a1 += mo * sWo1[cch];
        }
#pragma unroll
        for (int off = 32; off; off >>= 1) {
            a0 += __shfl_xor(a0, off);
            a1 += __shfl_xor(a1, off);
        }
        if (lane == 0) { spre0[idx] = a0 + bo0; spre1[idx] = a1 + bo1; }
    }
    __syncthreads();

    {
        double v[4] = {0.0, 0.0, 0.0, 0.0};
        if (tid < 3 * NPAT) {
            const double n = (double)snn[tid];
            const double p0 = (double)spre0[tid], p1 = (double)spre1[tid];
            v[0] = n * p0; v[1] = n * p0 * p0; v[2] = n * p1; v[3] = n * p1 * p1;
        }
#pragma unroll
        for (int off = 32; off; off >>= 1)
#pragma unroll
            for (int s = 0; s < 4; ++s) v[s] += __shfl_xor(v[s], off);
        if (lane == 0)
#pragma unroll
            for (int s = 0; s < 4; ++s) wpart[wv][s] = v[s];
        __syncthreads();
        if (wv == 0) {
            double aq[4];
#pragma unroll
            for (int s = 0; s < 4; ++s) aq[s] = (lane < 16) ? wpart[lane][s] : 0.0;
#pragma unroll
            for (int off = 8; off; off >>= 1)
#pragma unroll
                for (int s = 0; s < 4; ++s) aq[s] += __shfl_xor(aq[s], off);
            if (lane == 0)
#pragma unroll
                for (int s = 0; s < 4; ++s) dstat[2 + s] = aq[s];
        }
        __syncthreads();
    }

    if (tid < 3 * NPAT) {
        const double m0 = dstat[2] / (3.0 * (double)CNT);
        const double v0 = dstat[3] / (3.0 * (double)CNT) - m0 * m0;
        const double m1 = dstat[4] / (3.0 * (double)CNT);
        const double v1 = dstat[5] / (3.0 * (double)CNT) - m1 * m1;
        const float sc0 = go[0] * rsqrtf((float)v0 + EPS);
        const float sc1 = go[1] * rsqrtf((float)v1 + EPS);
        out_tab[tid * 2 + 0] = sc0 * (spre0[tid] - (float)m0) + beo[0];
        out_tab[tid * 2 + 1] = sc1 * (spre1[tid] - (float)m1) + beo[1];
    }
}

__global__ __launch_bounds__(256) void k_write2(const ushort_t* __restrict__ codes,
                                                const float* __restrict__ out_tab,
                                                float* __restrict__ out) {
    __shared__ float2 tb[3 * NPAT];
    const int tid = threadIdx.x;
    for (int i = tid; i < 3 * NPAT; i += 256) tb[i] = ((const float2*)out_tab)[i];
    __syncthreads();
    const size_t gidx = (size_t)blockIdx.x * 256 + tid;
    const ushort4 cv = ((const ushort4*)codes)[gidx];
    const int cc[4] = {cv.x, cv.y, cv.z, cv.w};
    union { float f[24]; float4 v[6]; } u;
#pragma unroll
    for (int r = 0; r < 4; ++r) {
        const int qd = cc[r] & 0xff, qp = cc[r] >> 8;
        const float2 v0 = tb[qd], v1 = tb[NPAT + qd], v2 = tb[2 * NPAT + qp];
        u.f[r * 6 + 0] = v0.x; u.f[r * 6 + 1] = v0.y;
        u.f[r * 6 + 2] = v1.x; u.f[r * 6 + 3] = v1.y;
        u.f[r * 6 + 4] = v2.x; u.f[r * 6 + 5] = v2.y;
    }
    float4* o = (float4*)(out + gidx * 24);
#pragma unroll
    for (int r = 0; r < 6; ++r) o[r] = u.v[r];
}

// =============================================================================
extern "C" void kernel_launch(void* const* d_in, const int* in_sizes, int n_in,
                              void* d_out, int out_size, void* d_ws, size_t ws_size,
                              hipStream_t stream) {
    (void)in_sizes; (void)n_in; (void)out_size;
    const float* x = (const float*)d_in[0];
    const int* perms = (const int*)d_in[1];

    PtrPack pk;
    for (int j = 0; j < 3; ++j)
        for (int s = 0; s < 6; ++s)
            pk.p[6 * j + s] = (const float*)d_in[2 + 6 * j + s];

    const float* Wm  = (const float*)d_in[20];
    const float* gm  = (const float*)d_in[22];
    const float* bem = (const float*)d_in[23];
    const float* Wo  = (const float*)d_in[24];
    const float* bo  = (const float*)d_in[25];
    const float* go  = (const float*)d_in[26];
    const float* beo = (const float*)d_in[27];

    // coop ws layout
    const size_t OFF_PART = 0;                 // 320*256 u32 = 327680 B
    const size_t OFF_ETAB = 327680;            // 480 f32
    const size_t OFF_HRF  = 329600;            // 480 f32
    const size_t OFF_OUTT = 331520;            // 960 f32 -> end 335360
    // fallback extra
    const size_t OFF_HRU   = 335360;           // 320 u32
    const size_t OFF_CODES = 336640;           // 1M u16 = 2 MB
    const size_t NEED = OFF_CODES + (size_t)BATCH * SEQL * 2;

    int dev = 0, coop = 0;
    hipGetDevice(&dev);
    hipDeviceGetAttribute(&coop, hipDeviceAttributeCooperativeLaunch, dev);

    if (coop && ws_size >= NEED) {
        CoopArgs ka;
        ka.x = x; ka.perms = perms; ka.pk = pk;
        ka.Wm = Wm; ka.gm = gm; ka.bem = bem;
        ka.Wo = Wo; ka.bo = bo; ka.go = go; ka.beo = beo;
        ka.part    = (uint*)((char*)d_ws + OFF_PART);
        ka.e_tab   = (float*)((char*)d_ws + OFF_ETAB);
        ka.hrf     = (float*)((char*)d_ws + OFF_HRF);
        ka.out_tab = (float*)((char*)d_ws + OFF_OUTT);
        ka.out     = (float*)d_out;
        void* args[] = { &ka };
        hipLaunchCooperativeKernel((const void*)k_coop, dim3(BATCH), dim3(512),
                                   args, 0, stream);
    } else {
        uint*     part    = (uint*)((char*)d_ws + OFF_PART);
        float*    e_tab   = (float*)((char*)d_ws + OFF_ETAB);
        float*    out_tab = (float*)((char*)d_ws + OFF_OUTT);
        uint*     hr      = (uint*)((char*)d_ws + OFF_HRU);
        ushort_t* codes   = (ushort_t*)((char*)d_ws + OFF_CODES);

        k_prep<<<BATCH, 512, 0, stream>>>(x, perms, part, codes);
        k_etab2<<<120, 256, 0, stream>>>(pk, part, e_tab, hr);
        k_outtab2<<<1, 1024, 0, stream>>>(hr, e_tab, Wm, gm, bem, Wo, bo, go, beo, out_tab);
        k_write2<<<1024, 256, 0, stream>>>(codes, out_tab, (float*)d_out);
    }
}

// Round 5
// 88.787 us; speedup vs baseline: 1.6531x; 1.6531x over previous
//
#include <hip/hip_runtime.h>
#include <hip/hip_bf16.h>
#include <math.h>

#define BATCH 256
#define SEQL  4096
#define DIMC  256
#define NPAT  160
#define CNT   (BATCH * SEQL)     // per-stream element count (over B,L)
#define EPS   1e-3f

typedef unsigned int uint;
typedef unsigned short ushort_t;

// ---------------- shared helpers ----------------------------------------------
__device__ __forceinline__ int pad_mask(int type) {
    return (type == 0) ? 0 : (type == 1) ? 3 : (type == 2) ? 1 : (type == 3) ? 16 : 24;
}

// tap value for extended-pattern q, index k in [0,6): k==5 is the constant 1.
__device__ __forceinline__ float tap6(int q, int k) {
    if (k == 5) return 1.0f;
    const int type = q >> 5, bits = q & 31;
    const int pm = pad_mask(type);
    if ((pm >> k) & 1) return 0.0f;
    return ((bits >> k) & 1) ? 1.0f : -1.0f;
}

__device__ __forceinline__ int tri_idx(int k, int l) {
    return k * 6 - (k * (k - 1)) / 2 + (l - k);
}

__device__ __forceinline__ float fast_elu(float x) {
    return x > 0.0f ? x : (__expf(x) - 1.0f);
}

__device__ __forceinline__ int pat_type(int t) {
    if (t >= 2 && t < SEQL - 2) return 0;
    if (t == 0) return 1;
    if (t == 1) return 2;
    if (t == SEQL - 2) return 3;
    return 4;
}

struct PtrPack { const float* p[18]; };  // per stream: Wc, bc, g, be, Wf, bf

// =============================================================================
// k_prep: bit-pack rows, emit per-position pattern codes + per-block partial
// histograms. 256 blocks (one row each) x 512 threads.  [proven round 3]
// =============================================================================
__global__ __launch_bounds__(512) void k_prep(const float* __restrict__ x,
                                              const int* __restrict__ perms,
                                              uint* __restrict__ part,
                                              ushort_t* __restrict__ codes) {
    __shared__ uint xw[130];    // bit-packed row, 1-word zero sentinel each end
    __shared__ uint xwI[130];
    __shared__ uint h[2 * NPAT];
    const int b = blockIdx.x, tid = threadIdx.x;
    const int lane = tid & 63;

    for (int i = tid; i < 2 * NPAT; i += 512) h[i] = 0;
    if (tid < 2) { xw[tid * 129] = 0; xwI[tid * 129] = 0; }

    const float* xr = x + (size_t)b * SEQL;
    const int* pr = perms + (size_t)b * SEQL;

#pragma unroll
    for (int it = 0; it < 8; ++it) {
        const int i = it * 512 + tid;
        const unsigned long long m = __ballot(xr[i] > 0.5f);
        if (lane == 0) {
            const int w = 1 + ((it * 512 + (tid & ~63)) >> 5);
            xw[w] = (uint)m;
            xw[w + 1] = (uint)(m >> 32);
        }
    }
    __syncthreads();
#pragma unroll
    for (int it = 0; it < 8; ++it) {
        const int i = it * 512 + tid;
        const int p = pr[i];
        const unsigned long long m = __ballot(((xw[1 + (p >> 5)] >> (p & 31)) & 1u) != 0u);
        if (lane == 0) {
            const int w = 1 + ((it * 512 + (tid & ~63)) >> 5);
            xwI[w] = (uint)m;
            xwI[w + 1] = (uint)(m >> 32);
        }
    }
    __syncthreads();

    const int t0 = tid * 8;
    const int w = (t0 + 30) >> 5;
    const int sh0 = (t0 + 30) & 31;
    const unsigned long long Wd = (unsigned long long)xw[w] | ((unsigned long long)xw[w + 1] << 32);
    const unsigned long long Wi = (unsigned long long)xwI[w] | ((unsigned long long)xwI[w + 1] << 32);
    int c[8];
#pragma unroll
    for (int r = 0; r < 8; ++r) {
        const int t = t0 + r;
        const int type = pat_type(t);
        const int qd = type * 32 + (int)((Wd >> (sh0 + r)) & 31ull);
        const int qp = type * 32 + (int)((Wi >> (sh0 + r)) & 31ull);
        atomicAdd(&h[qd], 1u);
        atomicAdd(&h[NPAT + qp], 1u);
        c[r] = qd | (qp << 8);
    }
    uint4 cv;
    cv.x = (uint)(c[0] | (c[1] << 16));
    cv.y = (uint)(c[2] | (c[3] << 16));
    cv.z = (uint)(c[4] | (c[5] << 16));
    cv.w = (uint)(c[6] | (c[7] << 16));
    *(uint4*)(codes + (size_t)b * SEQL + t0) = cv;
    __syncthreads();

    if (tid < 2 * NPAT) part[(size_t)tid * 256 + b] = h[tid];
}

// =============================================================================
// k_fused: every block redundantly computes the full table pipeline in LDS
// (deterministic, identical across blocks), then writes its row of output.
// 256 blocks x 1024 threads (16 waves).
// =============================================================================
__global__ __launch_bounds__(1024) void k_fused(PtrPack pk,
                                                const float* __restrict__ Wm,
                                                const float* __restrict__ gm,
                                                const float* __restrict__ bem,
                                                const float* __restrict__ Wo,
                                                const float* __restrict__ bo,
                                                const float* __restrict__ go,
                                                const float* __restrict__ beo,
                                                const uint* __restrict__ part,
                                                const ushort_t* __restrict__ codes,
                                                float* __restrict__ out) {
    const int tid = threadIdx.x;
    const int w = tid >> 6, lane = tid & 63;   // 16 waves

    __shared__ float sh_hist[2 * NPAT];        // reduced histogram (f32, exact)
    __shared__ float m6p[3][21][8];
    __shared__ float sM6[3][21];
    __shared__ float sa[3][5][DIMC];
    __shared__ float sb[3][DIMC];
    __shared__ float swf[3][DIMC];
    __shared__ float se[480], snn[480];
    __shared__ float spre0[480], spre1[480];
    __shared__ float sA[DIMC], sB[DIMC], sWo0[DIMC], sWo1[DIMC];
    __shared__ double wpart[16][4];
    __shared__ double dstat[6];
    __shared__ float2 tb[480];

    // ---- T1: reduce per-block partials -> histogram (16 waves x 20 bins) ----
    for (int bl = w * 20; bl < w * 20 + 20; ++bl) {
        const uint4 v = *(const uint4*)&part[(size_t)bl * 256 + lane * 4];
        uint s = v.x + v.y + v.z + v.w;
#pragma unroll
        for (int off = 32; off; off >>= 1) s += __shfl_xor(s, off);
        if (lane == 0) sh_hist[bl] = (float)s;
    }
    __syncthreads();

    // ---- T2: M6 second-moment matrices, one per stream ----------------------
    if (tid < 504) {
        const int j = tid / 168, r = tid % 168;
        const int e = r >> 3, prt = r & 7;
        int k = 0, rem = e;
        while (rem > 5 - k) { rem -= 6 - k; ++k; }
        const int l = k + rem;
        const float* hj = sh_hist + ((j == 2) ? NPAT : 0);
        float S = 0.0f;
        for (int q = prt * 20; q < prt * 20 + 20; ++q)
            S += hj[q] * tap6(q, k) * tap6(q, l);
        m6p[j][e][prt] = S;
    }
    __syncthreads();
    if (tid < 63) {
        const int j = tid / 21, e = tid % 21;
        float S = 0.0f;
#pragma unroll
        for (int p = 0; p < 8; ++p) S += m6p[j][e][p];
        sM6[j][e] = S;
    }
    __syncthreads();

    // ---- T3: per-channel BN coefficients for all 3 streams ------------------
    if (tid < 768) {
        const int j = tid >> 8, c = tid & 255;
        const float* Wc = pk.p[6 * j + 0];
        const float* bc = pk.p[6 * j + 1];
        const float* g  = pk.p[6 * j + 2];
        const float* be = pk.p[6 * j + 3];
        const float* Wf = pk.p[6 * j + 4];
        float w6[6];
#pragma unroll
        for (int k = 0; k < 5; ++k) w6[k] = Wc[k * DIMC + c];
        w6[5] = bc[c];
        double Ey = 0.0, Ey2 = 0.0;
        int e = 0;
        for (int k = 0; k < 6; ++k) {
            Ey += (double)w6[k] * (double)sM6[j][tri_idx(k, 5)];
            for (int l = k; l < 6; ++l, ++e) {
                const double p = (double)w6[k] * (double)w6[l] * (double)sM6[j][e];
                Ey2 += (l == k) ? p : 2.0 * p;
            }
        }
        const double mean = Ey / (double)CNT;
        const double var = Ey2 / (double)CNT - mean * mean;
        const float scale = g[c] * rsqrtf((float)var + EPS);
#pragma unroll
        for (int k = 0; k < 5; ++k) sa[j][k][c] = scale * w6[k];
        sb[j][c] = scale * (w6[5] - (float)mean) + be[c];
        swf[j][c] = Wf[c];
    }
    if (tid < 480) {
        const int j = tid / 160, q = tid % 160;
        snn[tid] = sh_hist[((j == 2) ? NPAT : 0) + q];
    }
    __syncthreads();

    // ---- T4: e-table, one wave per pattern (stride 16) ----------------------
    for (int p = w; p < 480; p += 16) {
        const int j = p / 160, q = p % 160;
        float tk[5];
#pragma unroll
        for (int k = 0; k < 5; ++k) tk[k] = tap6(q, k);
        float acc = 0.0f;
#pragma unroll
        for (int i = 0; i < 4; ++i) {
            const int c = lane + 64 * i;
            float bn = sb[j][c];
#pragma unroll
            for (int k = 0; k < 5; ++k) bn += tk[k] * sa[j][k][c];
            acc += fast_elu(bn) * swf[j][c];
        }
#pragma unroll
        for (int off = 32; off; off >>= 1) acc += __shfl_xor(acc, off);
        if (lane == 0) se[p] = acc + pk.p[6 * j + 5][0];
    }
    __syncthreads();

    // ---- T5: yt mean/var (weighted f64 over 480 bins) -----------------------
    {
        double d1 = 0.0, d2 = 0.0;
        if (tid < 480) {
            const double n = (double)snn[tid], e = (double)se[tid];
            d1 = n * e; d2 = n * e * e;
        }
#pragma unroll
        for (int off = 32; off; off >>= 1) {
            d1 += __shfl_xor(d1, off);
            d2 += __shfl_xor(d2, off);
        }
        if (lane == 0) { wpart[w][0] = d1; wpart[w][1] = d2; }
        __syncthreads();
        if (w == 0) {
            double a = (lane < 16) ? wpart[lane][0] : 0.0;
            double b2 = (lane < 16) ? wpart[lane][1] : 0.0;
#pragma unroll
            for (int off = 8; off; off >>= 1) {
                a += __shfl_xor(a, off);
                b2 += __shfl_xor(b2, off);
            }
            if (lane == 0) { dstat[0] = a; dstat[1] = b2; }
        }
        __syncthreads();
    }
    const double mean_yt = dstat[0] / (3.0 * (double)CNT);
    const double var_yt  = dstat[1] / (3.0 * (double)CNT) - mean_yt * mean_yt;

    // ---- T6: middle-unit affine coefficients --------------------------------
    if (tid < DIMC) {
        const float wm = Wm[tid];
        sA[tid] = gm[tid] * wm * rsqrtf(wm * wm * (float)var_yt + EPS);
        sB[tid] = bem[tid];
        sWo0[tid] = Wo[tid * 2 + 0];
        sWo1[tid] = Wo[tid * 2 + 1];
    }
    __syncthreads();

    // ---- T7: output pre-activations per pattern -----------------------------
    const float bo0 = bo[0], bo1 = bo[1];
    for (int p = w; p < 480; p += 16) {
        const float du = se[p] - (float)mean_yt;
        float a0 = 0.0f, a1 = 0.0f;
#pragma unroll
        for (int i = 0; i < 4; ++i) {
            const int c = lane + 64 * i;
            const float mo = fast_elu(sA[c] * du + sB[c]);
            a0 += mo * sWo0[c];
            a1 += mo * sWo1[c];
        }
#pragma unroll
        for (int off = 32; off; off >>= 1) {
            a0 += __shfl_xor(a0, off);
            a1 += __shfl_xor(a1, off);
        }
        if (lane == 0) { spre0[p] = a0 + bo0; spre1[p] = a1 + bo1; }
    }
    __syncthreads();

    // ---- T8: output BN stats (4 weighted f64 sums) --------------------------
    {
        double v4[4] = {0.0, 0.0, 0.0, 0.0};
        if (tid < 480) {
            const double n = (double)snn[tid];
            const double p0 = (double)spre0[tid], p1 = (double)spre1[tid];
            v4[0] = n * p0; v4[1] = n * p0 * p0; v4[2] = n * p1; v4[3] = n * p1 * p1;
        }
#pragma unroll
        for (int off = 32; off; off >>= 1)
#pragma unroll
            for (int s = 0; s < 4; ++s) v4[s] += __shfl_xor(v4[s], off);
        if (lane == 0)
#pragma unroll
            for (int s = 0; s < 4; ++s) wpart[w][s] = v4[s];
        __syncthreads();
        if (w == 0) {
            double a[4];
#pragma unroll
            for (int s = 0; s < 4; ++s) a[s] = (lane < 16) ? wpart[lane][s] : 0.0;
#pragma unroll
            for (int off = 8; off; off >>= 1)
#pragma unroll
                for (int s = 0; s < 4; ++s) a[s] += __shfl_xor(a[s], off);
            if (lane == 0)
#pragma unroll
                for (int s = 0; s < 4; ++s) dstat[2 + s] = a[s];
        }
        __syncthreads();
    }

    // ---- T9: final output table ---------------------------------------------
    if (tid < 480) {
        const double m0 = dstat[2] / (3.0 * (double)CNT);
        const double v0 = dstat[3] / (3.0 * (double)CNT) - m0 * m0;
        const double m1 = dstat[4] / (3.0 * (double)CNT);
        const double v1 = dstat[5] / (3.0 * (double)CNT) - m1 * m1;
        const float sc0 = go[0] * rsqrtf((float)v0 + EPS);
        const float sc1 = go[1] * rsqrtf((float)v1 + EPS);
        tb[tid] = make_float2(sc0 * (spre0[tid] - (float)m0) + beo[0],
                              sc1 * (spre1[tid] - (float)m1) + beo[1]);
    }
    __syncthreads();

    // ---- T10: stream this block's row from codes ----------------------------
    const int b = blockIdx.x;
    const ushort4 cv = ((const ushort4*)(codes + (size_t)b * SEQL))[tid];
    const int cc[4] = {cv.x, cv.y, cv.z, cv.w};
    union { float f[24]; float4 v[6]; } u;
#pragma unroll
    for (int r = 0; r < 4; ++r) {
        const int qd = cc[r] & 0xff, qp = cc[r] >> 8;
        const float2 v0 = tb[qd], v1 = tb[NPAT + qd], v2 = tb[2 * NPAT + qp];
        u.f[r * 6 + 0] = v0.x; u.f[r * 6 + 1] = v0.y;
        u.f[r * 6 + 2] = v1.x; u.f[r * 6 + 3] = v1.y;
        u.f[r * 6 + 4] = v2.x; u.f[r * 6 + 5] = v2.y;
    }
    float4* o = (float4*)(out + ((size_t)b * SEQL + (size_t)tid * 4) * 6);
#pragma unroll
    for (int r = 0; r < 6; ++r) o[r] = u.v[r];
}

// =============================================================================
extern "C" void kernel_launch(void* const* d_in, const int* in_sizes, int n_in,
                              void* d_out, int out_size, void* d_ws, size_t ws_size,
                              hipStream_t stream) {
    (void)in_sizes; (void)n_in; (void)out_size; (void)ws_size;
    const float* x = (const float*)d_in[0];
    const int* perms = (const int*)d_in[1];

    PtrPack pk;
    for (int j = 0; j < 3; ++j)
        for (int s = 0; s < 6; ++s)
            pk.p[6 * j + s] = (const float*)d_in[2 + 6 * j + s];

    const float* Wm  = (const float*)d_in[20];
    const float* gm  = (const float*)d_in[22];
    const float* bem = (const float*)d_in[23];
    const float* Wo  = (const float*)d_in[24];
    const float* bo  = (const float*)d_in[25];
    const float* go  = (const float*)d_in[26];
    const float* beo = (const float*)d_in[27];

    // ws layout: [0, 320K) u32 part[320][256]; [320K, 320K+2M) u16 codes
    uint*     part  = (uint*)d_ws;
    ushort_t* codes = (ushort_t*)((char*)d_ws + 327680);

    k_prep<<<BATCH, 512, 0, stream>>>(x, perms, part, codes);
    k_fused<<<BATCH, 1024, 0, stream>>>(pk, Wm, gm, bem, Wo, bo, go, beo,
                                        part, codes, (float*)d_out);
}